// Round 1
// baseline (8598.177 us; speedup 1.0000x reference)
//
#include <hip/hip_runtime.h>

// Problem constants (from reference): B=128, S=1024, F_IN=128, H=256, BB=256, F_OUT=128
#define Bn   128
#define Sn   1024
#define FIN  128
#define Hn   256
#define FOUT 128
#define KBB  384   // F_IN + H

typedef _Float16 h2 __attribute__((ext_vector_type(2)));
typedef _Float16 h8 __attribute__((ext_vector_type(8)));

// d_ws layout (in halves):
//   Wb_p   [48][256][8]   : backbone weights, (k,j) packed as k-blocks of 8 -> 98304 halves
//   W4_p   [32][1024][8]  : concat(ff1,ff2,ta,tb) along N -> 262144 halves
//   Wout_p [32][128][8]   : output projection -> 32768 halves
#define WB_OFF 0
#define W4_OFF 98304
#define WO_OFF 360448
#define WS_HALVES 393216

__device__ __forceinline__ float dot2f(h2 a, h2 b, float c) {
#if __has_builtin(__builtin_amdgcn_fdot2)
  return __builtin_amdgcn_fdot2(a, b, c, false);   // v_dot2_f32_f16
#else
  return c + (float)a[0] * (float)b[0] + (float)a[1] * (float)b[1];
#endif
}

__device__ __forceinline__ float dot8f(h8 v, h8 w, float c) {
  h2 v0 = {v[0], v[1]}, v1 = {v[2], v[3]}, v2 = {v[4], v[5]}, v3 = {v[6], v[7]};
  h2 w0 = {w[0], w[1]}, w1 = {w[2], w[3]}, w2 = {w[4], w[5]}, w3 = {w[6], w[7]};
  c = dot2f(v0, w0, c);
  c = dot2f(v1, w1, c);
  c = dot2f(v2, w2, c);
  c = dot2f(v3, w3, c);
  return c;
}

// 4 independent partial accumulators (breaks the fma dependency chain)
__device__ __forceinline__ void dot8_4(h8 v, h8 w, float& c0, float& c1, float& c2, float& c3) {
  h2 v0 = {v[0], v[1]}, v1 = {v[2], v[3]}, v2 = {v[4], v[5]}, v3 = {v[6], v[7]};
  h2 w0 = {w[0], w[1]}, w1 = {w[2], w[3]}, w2 = {w[4], w[5]}, w3 = {w[6], w[7]};
  c0 = dot2f(v0, w0, c0);
  c1 = dot2f(v1, w1, c1);
  c2 = dot2f(v2, w2, c2);
  c3 = dot2f(v3, w3, c3);
}

// Pack all fp32 weights into fp16, layout [k/8][j][k%8] so each thread's 8
// k-consecutive weights for its column j are one 16B global_load_dwordx4,
// coalesced across consecutive j. Runs every launch (d_ws is re-poisoned).
__global__ __launch_bounds__(256) void pack_w(
    const float* __restrict__ Wb, const float* __restrict__ W1,
    const float* __restrict__ W2, const float* __restrict__ W3,
    const float* __restrict__ W4, const float* __restrict__ Wo,
    _Float16* __restrict__ ws) {
  int p = blockIdx.x * 256 + threadIdx.x;
  if (p >= WS_HALVES) return;
  float v;
  if (p < W4_OFF) {                       // backbone [384,256] row-major
    int r = p & 7, j = (p >> 3) & 255;
    int k = ((p >> 11) << 3) | r;
    v = Wb[k * 256 + j];
  } else if (p < WO_OFF) {                // heads concat: N = [ff1|ff2|ta|tb]
    int q = p - W4_OFF;
    int r = q & 7, j = (q >> 3) & 1023;
    int k = ((q >> 13) << 3) | r;
    int jj = j & 255;
    const float* Ws = (j < 256) ? W1 : (j < 512) ? W2 : (j < 768) ? W3 : W4;
    v = Ws[k * 256 + jj];
  } else {                                // Wout [256,128]
    int q = p - WO_OFF;
    int r = q & 7, j = (q >> 3) & 127;
    int k = ((q >> 10) << 3) | r;
    v = Wo[k * 128 + j];
  }
  ws[p] = (_Float16)v;
}

// One workgroup (256 threads = 4 waves) per batch element; full S=1024 recurrence.
// Shared x/h/z vectors live in LDS (broadcast reads are bank-conflict-free);
// weights stream from L2 as fp16 dwordx4; all accumulation in fp32.
__global__ __launch_bounds__(256) void cfc_kernel(
    const float* __restrict__ x, const float* __restrict__ ts,
    const float* __restrict__ bb, const float* __restrict__ bf1,
    const float* __restrict__ bf2, const float* __restrict__ bta,
    const float* __restrict__ btb, const float* __restrict__ bo,
    const _Float16* __restrict__ ws, float* __restrict__ out) {
  __shared__ __align__(16) _Float16 xh[KBB];  // [0,128): x_t  [128,384): h
  __shared__ __align__(16) _Float16 zb[Hn];   // backbone activations z

  const int b = blockIdx.x, j = threadIdx.x;
  const _Float16* Wb_p = ws + WB_OFF;
  const _Float16* W4_p = ws + W4_OFF;
  const _Float16* Wo_p = ws + WO_OFF;

  xh[FIN + j] = (_Float16)0.f;  // h0 = 0 (256 threads cover all of H)

  const float bbj = bb[j];
  const float g1b = bf1[j], g2b = bf2[j], g3b = bta[j], g4b = btb[j];
  const float boj = (j < FOUT) ? bo[j] : 0.f;

  const float* xrow  = x  + (size_t)b * Sn * FIN;
  const float* tsrow = ts + (size_t)b * Sn;
  float*       orow  = out + (size_t)b * Sn * FOUT;

  for (int t = 0; t < Sn; ++t) {
    // stage x_t into LDS (h part already there from previous step)
    if (j < FIN) xh[j] = (_Float16)xrow[(size_t)t * FIN + j];
    const float tt = tsrow[t];
    __syncthreads();

    // ---- backbone: z_j = tanh(bb_j + sum_k [x_t,h] (k) * Wb[k][j]), K=384 ----
    float a0 = bbj, a1 = 0.f, a2 = 0.f, a3 = 0.f;
#pragma unroll 4
    for (int k8 = 0; k8 < 48; ++k8) {
      h8 v = *(const h8*)&xh[k8 * 8];                      // LDS broadcast
      h8 w = *(const h8*)(Wb_p + ((k8 * 256 + j) << 3));   // coalesced 16B
      dot8_4(v, w, a0, a1, a2, a3);
    }
    zb[j] = (_Float16)tanhf(a0 + a1 + a2 + a3);
    __syncthreads();

    // ---- 4 heads fused: [ff1|ff2|ta|tb] = z @ W4, K=256 ----
    float g1 = g1b, g2 = g2b, g3 = g3b, g4 = g4b;
#pragma unroll 2
    for (int k8 = 0; k8 < 32; ++k8) {
      h8 v = *(const h8*)&zb[k8 * 8];
      const _Float16* wp = W4_p + (k8 << 13) + (j << 3);
      h8 w1 = *(const h8*)(wp);
      h8 w2 = *(const h8*)(wp + 2048);
      h8 w3 = *(const h8*)(wp + 4096);
      h8 w4 = *(const h8*)(wp + 6144);
      g1 = dot8f(v, w1, g1);   // 4 independent chains -> ILP 4
      g2 = dot8f(v, w2, g2);
      g3 = dot8f(v, w3, g3);
      g4 = dot8f(v, w4, g4);
    }
    const float f1 = tanhf(g1), f2 = tanhf(g2);
    const float sg = 1.f / (1.f + __expf(-(g3 * tt + g4)));
    const float hn = f1 * (1.f - sg) + sg * f2;
    xh[FIN + j] = (_Float16)hn;   // h for next step + input to y
    __syncthreads();

    // ---- y = h_new @ Wout + bout (waves 0-1 only; wave-uniform branch) ----
    if (j < FOUT) {
      float y0 = boj, y1 = 0.f, y2 = 0.f, y3 = 0.f;
#pragma unroll 4
      for (int k8 = 0; k8 < 32; ++k8) {
        h8 v = *(const h8*)&xh[FIN + k8 * 8];
        h8 w = *(const h8*)(Wo_p + (k8 << 10) + (j << 3));
        dot8_4(v, w, y0, y1, y2, y3);
      }
      orow[(size_t)t * FOUT + j] = y0 + y1 + y2 + y3;
    }
    // no barrier here: next iter writes xh[0,128) (disjoint from y's reads),
    // and h-reads in next backbone are protected by the top-of-loop barrier.
  }
}

extern "C" void kernel_launch(void* const* d_in, const int* in_sizes, int n_in,
                              void* d_out, int out_size, void* d_ws, size_t ws_size,
                              hipStream_t stream) {
  const float* x   = (const float*)d_in[0];
  const float* ts  = (const float*)d_in[1];
  const float* Wb  = (const float*)d_in[2];
  const float* bb  = (const float*)d_in[3];
  const float* W1  = (const float*)d_in[4];
  const float* bf1 = (const float*)d_in[5];
  const float* W2  = (const float*)d_in[6];
  const float* bf2 = (const float*)d_in[7];
  const float* W3  = (const float*)d_in[8];
  const float* bta = (const float*)d_in[9];
  const float* W4  = (const float*)d_in[10];
  const float* btb = (const float*)d_in[11];
  const float* Wo  = (const float*)d_in[12];
  const float* bo  = (const float*)d_in[13];
  float* out = (float*)d_out;
  _Float16* ws = (_Float16*)d_ws;

  pack_w<<<WS_HALVES / 256, 256, 0, stream>>>(Wb, W1, W2, W3, W4, Wo, ws);
  cfc_kernel<<<Bn, 256, 0, stream>>>(x, ts, bb, bf1, bf2, bta, btb, bo, ws, out);
}